// Round 6
// baseline (531.397 us; speedup 1.0000x reference)
//
#include <hip/hip_runtime.h>

#define N_NODES 50000
#define N_REL 16
#define N_BASIS 8
#define N_EDGES 800000
#define CAP 64              // bucket capacity; deg ~ Poisson(16), P(>64) ~ 1e-19

#define WREL_BLOCKS 340     // (17*4096 + 17*1024)/256
#define ZERO_BLOCKS 49      // ceil(12504 int4 / 256)
#define XBF_BLOCKS 1563     // ceil(400000 / 256)  (50000*64 / 8 per thread)
#define SC_BLOCKS 3125      // 800000 / 256
#define AGG_BLOCKS 3125     // 50000 / 16 exact

typedef short s8v __attribute__((ext_vector_type(8)));    // 8 bf16 MFMA A/B frag
typedef float f4v __attribute__((ext_vector_type(4)));    // 4 fp32 MFMA C/D frag

__device__ inline unsigned short f2bf(float f) {
    union { float f; unsigned u; } v; v.f = f;
    unsigned r = (v.u + 0x7FFFu + ((v.u >> 16) & 1u)) >> 16;   // RNE
    return (unsigned short)r;
}

// a[0..7] += inv * (8 bf16 packed in int4)   (R0-proven helper for k_agg2)
__device__ __forceinline__ void acc8(float* a, float inv, int4 p) {
    a[0] += inv * __int_as_float((int)((unsigned)p.x << 16));
    a[1] += inv * __int_as_float(p.x & (int)0xFFFF0000u);
    a[2] += inv * __int_as_float((int)((unsigned)p.y << 16));
    a[3] += inv * __int_as_float(p.y & (int)0xFFFF0000u);
    a[4] += inv * __int_as_float((int)((unsigned)p.z << 16));
    a[5] += inv * __int_as_float(p.z & (int)0xFFFF0000u);
    a[6] += inv * __int_as_float((int)((unsigned)p.w << 16));
    a[7] += inv * __int_as_float(p.w & (int)0xFFFF0000u);
}

// ---- pre-pass: wrel weights || cursor zero || x -> bf16 cast (R3-R5 verified) ----
__global__ __launch_bounds__(256) void k_pre(const float* __restrict__ x,
                                             const float* __restrict__ b1, const float* __restrict__ c1,
                                             const float* __restrict__ s1f,
                                             const float* __restrict__ b2, const float* __restrict__ c2,
                                             const float* __restrict__ s2f,
                                             unsigned short* __restrict__ w1T,
                                             unsigned short* __restrict__ w2T,
                                             unsigned short* __restrict__ xbf,
                                             int* __restrict__ cursor) {
    int bid = blockIdx.x;
    if (bid >= WREL_BLOCKS + ZERO_BLOCKS) {
        int i = (bid - WREL_BLOCKS - ZERO_BLOCKS) * 256 + threadIdx.x;
        if (i < 400000) {
            const float4* xs = (const float4*)x + (size_t)i * 2;
            float4 v0 = xs[0], v1 = xs[1];
            int4 w;
            w.x = (int)(((unsigned)f2bf(v0.y) << 16) | f2bf(v0.x));
            w.y = (int)(((unsigned)f2bf(v0.w) << 16) | f2bf(v0.z));
            w.z = (int)(((unsigned)f2bf(v1.y) << 16) | f2bf(v1.x));
            w.w = (int)(((unsigned)f2bf(v1.w) << 16) | f2bf(v1.z));
            *(int4*)(xbf + (size_t)i * 8) = w;
        }
        return;
    }
    if (bid >= WREL_BLOCKS) {
        int i = (bid - WREL_BLOCKS) * 256 + threadIdx.x;
        if (i < 12504) ((int4*)cursor)[i] = make_int4(0, 0, 0, 0);
        return;
    }
    int idx = bid * 256 + threadIdx.x;
    if (idx < 17 * 4096) {
        int r = idx >> 12, o = (idx >> 6) & 63, k = idx & 63;
        float acc = 0.f;
        if (r < 16) {
            #pragma unroll
            for (int b = 0; b < N_BASIS; b++) acc += c1[r * N_BASIS + b] * b1[b * 4096 + k * 64 + o];
        } else {
            acc = s1f[k * 64 + o];
        }
        w1T[idx] = f2bf(acc);
    } else {
        int idx2 = idx - 17 * 4096;
        if (idx2 < 17 * 1024) {
            int r = idx2 >> 10, o = (idx2 >> 6) & 15, k = idx2 & 63;
            float acc = 0.f;
            if (r < 16) {
                #pragma unroll
                for (int b = 0; b < N_BASIS; b++) acc += c2[r * N_BASIS + b] * b2[b * 1024 + k * 16 + o];
            } else {
                acc = s2f[k * 16 + o];
            }
            w2T[idx2] = f2bf(acc);
        }
    }
}

// ---- bucket scatter (R0-proven body) ----
__global__ __launch_bounds__(256) void k_scatter(const int* __restrict__ ei,
                                                 const int* __restrict__ et,
                                                 int* __restrict__ cursor,
                                                 int* __restrict__ sed) {
    int e = blockIdx.x * 256 + threadIdx.x;
    if (e < N_EDGES) {
        int src = ei[e];
        int dst = ei[N_EDGES + e];
        int t = et[e];
        int pos = atomicAdd(&cursor[dst], 1);
        if (pos < CAP) sed[dst * CAP + pos] = (t << 16) | src;
    }
}

// LDS for k_agg1t: 64KB f32 accumulators, overlaid (after the conv barrier dance)
// by the bf16 agg tiles + h tile. Total 65,536 B -> up to 2 blocks/CU.
struct AggU {
    union {
        float aggf[16][16][64];                    // [node][rel][dim], 65536 B
        struct {
            unsigned short aggbf[16][16][72];      // [rel][node][dim+pad], 36864 B
            char pad_[4096];
            unsigned short htile[16][72];          // h tile @ 40960, disjoint from aggbf
        } s;
    };
};

// ---- fused layer-1 agg + W1-MFMA + relu + layer-2 transform (t2, out-self) ----
// 1024 thr = 16 waves = 16 nodes/block. Walk: unsorted ds_add_f32 (no sort/flush),
// 2 edges/iter (32 lanes x 2 dims each). Stage-1 MFMA = R3-R5-proven mappings.
// Stage-2 = R0 k_aggt phase-2 (verified) with htile in LDS, 16 waves = 16 slots + self.
__global__ __launch_bounds__(1024) void k_agg1t(const int* __restrict__ cursor,
                                                const int* __restrict__ sed,
                                                const unsigned short* __restrict__ xbf,
                                                const unsigned short* __restrict__ w1T,
                                                const unsigned short* __restrict__ w2T,
                                                unsigned short* __restrict__ t2,
                                                float* __restrict__ out) {
    __shared__ AggU L;
    int tid = threadIdx.x;
    int wv = tid >> 6, lane = tid & 63;
    int nb = blockIdx.x * 16;
    int j = wv, n = nb + j;

    // zero own node's f32 slab (wave-local; same-wave LDS ordering covers the walk)
    {
        float4 z4 = make_float4(0.f, 0.f, 0.f, 0.f);
        float4* zp = (float4*)&L.aggf[j][0][0];
        #pragma unroll
        for (int c = 0; c < 4; c++) zp[c * 64 + lane] = z4;
    }

    int deg = cursor[n];
    deg = deg < CAP ? deg : CAP;
    int e_raw = sed[n * CAP + lane];
    bool act = lane < deg;

    // per-relation counts via ballots; lane r (r<16) holds cnt_r -> inv_r
    int cnt = 0;
    #pragma unroll
    for (int r = 0; r < 16; r++) {
        unsigned long long mask = __ballot(act && ((e_raw >> 16) == r));
        if (lane == r) cnt = (int)__popcll(mask);
    }
    float inv = 1.0f / (float)(cnt > 0 ? cnt : 1);
    float s_own = __shfl(inv, (e_raw >> 16) & 15);   // scale of own edge slot

    // walk: 2 edges per iteration; lane = (half: which edge, dl: 2 dims)
    int half = lane >> 5, dl = lane & 31;
    for (int k0 = 0; k0 < deg; k0 += 2) {
        int idx = k0 + half;
        int em = __shfl(e_raw, idx);
        float sm = __shfl(s_own, idx);
        if (idx < deg) {
            int sp = em & 0xFFFF;
            unsigned v = *(const unsigned*)(xbf + (size_t)sp * 64 + dl * 2);
            float f0 = __int_as_float((int)(v << 16));
            float f1 = __int_as_float((int)(v & 0xFFFF0000u));
            float* bp = &L.aggf[j][(em >> 16) & 15][dl * 2];
            atomicAdd(bp, f0 * sm);          // ds_add_f32: fire-and-forget
            atomicAdd(bp + 1, f1 * sm);
        }
    }

    // conv f32 -> bf16: read own node fully into regs (wave-local), barrier,
    // then write aggbf (overlays other nodes' dead f32), barrier.
    int d2 = lane & 31, rh = lane >> 5;     // dims {2*d2, 2*d2+1}, rels rh*8..rh*8+7
    float va[8], vb[8];
    #pragma unroll
    for (int rr = 0; rr < 8; rr++) {
        float2 v = *(const float2*)&L.aggf[j][rh * 8 + rr][d2 * 2];
        va[rr] = v.x; vb[rr] = v.y;
    }
    __syncthreads();
    #pragma unroll
    for (int rr = 0; rr < 8; rr++) {
        unsigned pk;
        asm("v_cvt_pk_bf16_f32 %0, %1, %2" : "=v"(pk) : "v"(va[rr]), "v"(vb[rr]));
        *(unsigned*)&L.s.aggbf[rh * 8 + rr][j][d2 * 2] = pk;
    }
    __syncthreads();

    int m = lane & 15, q = lane >> 4;
    int nn = nb + m;
    if (wv < 4) {   // stage 1: h = relu(Sum_r agg_r@W1_r + x@self1) -> htile LDS
        const unsigned short* wpA = w1T + (wv * 16 + m) * 64 + q * 8;   // A[o=wv*16+m][k]
        f4v D = (f4v){0.f, 0.f, 0.f, 0.f};
        #pragma unroll 4
        for (int r = 0; r < 16; r++) {
            s8v A0 = *(const s8v*)(wpA + r * 4096);
            s8v A1 = *(const s8v*)(wpA + r * 4096 + 32);
            s8v B0 = *(const s8v*)&L.s.aggbf[r][m][q * 8];
            s8v B1 = *(const s8v*)&L.s.aggbf[r][m][32 + q * 8];
            D = __builtin_amdgcn_mfma_f32_16x16x32_bf16(A0, B0, D, 0, 0, 0);
            D = __builtin_amdgcn_mfma_f32_16x16x32_bf16(A1, B1, D, 0, 0, 0);
        }
        {   // self term: relation slot 16, B straight from xbf
            s8v A0 = *(const s8v*)(wpA + 16 * 4096);
            s8v A1 = *(const s8v*)(wpA + 16 * 4096 + 32);
            s8v B0 = *(const s8v*)(xbf + (size_t)nn * 64 + q * 8);
            s8v B1 = *(const s8v*)(xbf + (size_t)nn * 64 + 32 + q * 8);
            D = __builtin_amdgcn_mfma_f32_16x16x32_bf16(A0, B0, D, 0, 0, 0);
            D = __builtin_amdgcn_mfma_f32_16x16x32_bf16(A1, B1, D, 0, 0, 0);
        }
        ushort4 o;
        o.x = f2bf(D[0] > 0.f ? D[0] : 0.f);
        o.y = f2bf(D[1] > 0.f ? D[1] : 0.f);
        o.z = f2bf(D[2] > 0.f ? D[2] : 0.f);
        o.w = f2bf(D[3] > 0.f ? D[3] : 0.f);
        *(ushort4*)&L.s.htile[m][wv * 16 + q * 4] = o;   // D col=m(node), row=q*4+i(dim)
    }
    __syncthreads();

    // stage 2 (R0 k_aggt phase-2): wave wv -> t2 slot wv; wave0 also slot16 -> out
    {
        const unsigned short* wp2 = w2T + m * 64 + q * 8;   // A[o=m][k]
        s8v b0 = *(const s8v*)&L.s.htile[m][q * 8];
        s8v b1 = *(const s8v*)&L.s.htile[m][32 + q * 8];
        {
            s8v A0 = *(const s8v*)(wp2 + (wv << 10));
            s8v A1 = *(const s8v*)(wp2 + (wv << 10) + 32);
            f4v acc = (f4v){0.f, 0.f, 0.f, 0.f};
            acc = __builtin_amdgcn_mfma_f32_16x16x32_bf16(A0, b0, acc, 0, 0, 0);
            acc = __builtin_amdgcn_mfma_f32_16x16x32_bf16(A1, b1, acc, 0, 0, 0);
            ushort4 o;
            o.x = f2bf(acc[0]); o.y = f2bf(acc[1]); o.z = f2bf(acc[2]); o.w = f2bf(acc[3]);
            *(ushort4*)(t2 + ((size_t)wv * N_NODES + nn) * 16 + q * 4) = o;
        }
        if (wv == 0) {   // self slot -> out (fp32)
            s8v A0 = *(const s8v*)(wp2 + (16 << 10));
            s8v A1 = *(const s8v*)(wp2 + (16 << 10) + 32);
            f4v acc = (f4v){0.f, 0.f, 0.f, 0.f};
            acc = __builtin_amdgcn_mfma_f32_16x16x32_bf16(A0, b0, acc, 0, 0, 0);
            acc = __builtin_amdgcn_mfma_f32_16x16x32_bf16(A1, b1, acc, 0, 0, 0);
            *(float4*)(out + (size_t)nn * 16 + q * 4) = make_float4(acc[0], acc[1], acc[2], acc[3]);
        }
    }
}

// ---- layer-2 aggregation (R0-proven body + 2 strictly-safer barriers):
//      16 lanes/node, 8 slots x unroll-2, LDS hist; gathers 32B t2 rows, += out ----
__global__ __launch_bounds__(256) void k_agg2(const int* __restrict__ cursor,
                                              const int* __restrict__ sed,
                                              const unsigned short* __restrict__ t2,
                                              float* __restrict__ out) {
    __shared__ int hist[16][16];
    int tid = threadIdx.x;
    int j = tid >> 4;          // node in block 0..15
    int sub = tid & 15;
    int n = blockIdx.x * 16 + j;   // 3125*16 = 50000 exact
    int deg = cursor[n];
    deg = deg < CAP ? deg : CAP;
    const int* bucket = sed + n * CAP;

    hist[j][sub] = 0;
    __syncthreads();
    for (int i = sub; i < deg; i += 16)
        atomicAdd(&hist[j][bucket[i] >> 16], 1);
    __syncthreads();

    int slot = sub >> 1;       // edge slot 0..7
    int d2 = sub & 1;          // dim half: 8 bf16
    float a[8];
    #pragma unroll
    for (int k = 0; k < 8; k++) a[k] = 0.f;
    for (int i = slot; i < deg; i += 16) {
        int e0 = bucket[i];
        bool has1 = (i + 8) < deg;
        int e1 = has1 ? bucket[i + 8] : e0;
        int t0 = e0 >> 16, s0 = e0 & 0xFFFF;
        int t1i = e1 >> 16, s1 = e1 & 0xFFFF;
        float inv0 = 1.0f / (float)hist[j][t0];
        float inv1 = has1 ? (1.0f / (float)hist[j][t1i]) : 0.f;
        int4 p0 = *(const int4*)(t2 + ((size_t)(t0 * N_NODES + s0)) * 16 + d2 * 8);
        int4 p1 = *(const int4*)(t2 + ((size_t)(t1i * N_NODES + s1)) * 16 + d2 * 8);
        acc8(a, inv0, p0);
        acc8(a, inv1, p1);
    }
    #pragma unroll
    for (int k = 0; k < 8; k++) {
        a[k] += __shfl_xor(a[k], 2, 64);
        a[k] += __shfl_xor(a[k], 4, 64);
        a[k] += __shfl_xor(a[k], 8, 64);
    }
    if (slot == 0) {
        float* p = out + (size_t)n * 16 + d2 * 8;
        float4 c0 = *(const float4*)p;
        float4 c1 = *(const float4*)(p + 4);
        c0.x += a[0]; c0.y += a[1]; c0.z += a[2]; c0.w += a[3];
        c1.x += a[4]; c1.y += a[5]; c1.z += a[6]; c1.w += a[7];
        *(float4*)p = c0;
        *(float4*)(p + 4) = c1;
    }
}

extern "C" void kernel_launch(void* const* d_in, const int* in_sizes, int n_in,
                              void* d_out, int out_size, void* d_ws, size_t ws_size,
                              hipStream_t stream) {
    const float* x      = (const float*)d_in[0];
    const float* bases1 = (const float*)d_in[1];
    const float* coeffs1= (const float*)d_in[2];
    const float* self1  = (const float*)d_in[3];
    const float* bases2 = (const float*)d_in[4];
    const float* coeffs2= (const float*)d_in[5];
    const float* self2  = (const float*)d_in[6];
    const int*   ei     = (const int*)d_in[7];
    const int*   et     = (const int*)d_in[8];
    float* out = (float*)d_out;

    char* ws = (char*)d_ws;
    int*            cursor = (int*)(ws + 0);                    //    200,064 (50,016 ints, zeroed)
    unsigned short* w1T    = (unsigned short*)(ws + 200064);    //    139,264
    unsigned short* w2T    = (unsigned short*)(ws + 339328);    //     34,816
    int*            sed    = (int*)(ws + 374144);               // 12,800,000 (50000 x 64 x 4B)
    unsigned short* xbf    = (unsigned short*)(ws + 13174144);  //  6,400,000 (50,000 rows x 128B)
    unsigned short* t2     = (unsigned short*)(ws + 19574144);  // 25,600,000 -> 45,174,144

    k_pre<<<WREL_BLOCKS + ZERO_BLOCKS + XBF_BLOCKS, 256, 0, stream>>>(
        x, bases1, coeffs1, self1, bases2, coeffs2, self2, w1T, w2T, xbf, cursor);
    k_scatter<<<SC_BLOCKS, 256, 0, stream>>>(ei, et, cursor, sed);
    k_agg1t<<<AGG_BLOCKS, 1024, 0, stream>>>(cursor, sed, xbf, w1T, w2T, t2, out);
    k_agg2<<<AGG_BLOCKS, 256, 0, stream>>>(cursor, sed, t2, out);
}

// Round 7
// 235.756 us; speedup vs baseline: 2.2540x; 2.2540x over previous
//
#include <hip/hip_runtime.h>

#define N_NODES 50000
#define N_REL 16
#define N_BASIS 8
#define N_EDGES 800000
#define CAP 64              // bucket capacity; deg ~ Poisson(16), P(>64) ~ 1e-19

#define WREL_BLOCKS 340     // (17*4096 + 17*1024)/256
#define ZERO_BLOCKS 49      // ceil(12504 int4 / 256)
#define XBF_BLOCKS 1563     // ceil(400000 / 256)  (50000*64 / 8 per thread)
#define SC_BLOCKS 3125      // 800000 / 256
#define AGG_BLOCKS 3125     // 50000 / 16 exact

typedef short s8v __attribute__((ext_vector_type(8)));    // 8 bf16 MFMA A/B frag
typedef float f4v __attribute__((ext_vector_type(4)));    // 4 fp32 MFMA C/D frag

__device__ inline unsigned short f2bf(float f) {
    union { float f; unsigned u; } v; v.f = f;
    unsigned r = (v.u + 0x7FFFu + ((v.u >> 16) & 1u)) >> 16;   // RNE
    return (unsigned short)r;
}
__device__ __forceinline__ float bfLO(int w) { return __int_as_float((int)((unsigned)w << 16)); }
__device__ __forceinline__ float bfHI(int w) { return __int_as_float(w & (int)0xFFFF0000u); }

// a[0..7] += inv * (8 bf16 packed in int4)   (R0-proven helper for k_agg2)
__device__ __forceinline__ void acc8(float* a, float inv, int4 p) {
    a[0] += inv * __int_as_float((int)((unsigned)p.x << 16));
    a[1] += inv * __int_as_float(p.x & (int)0xFFFF0000u);
    a[2] += inv * __int_as_float((int)((unsigned)p.y << 16));
    a[3] += inv * __int_as_float(p.y & (int)0xFFFF0000u);
    a[4] += inv * __int_as_float((int)((unsigned)p.z << 16));
    a[5] += inv * __int_as_float(p.z & (int)0xFFFF0000u);
    a[6] += inv * __int_as_float((int)((unsigned)p.w << 16));
    a[7] += inv * __int_as_float(p.w & (int)0xFFFF0000u);
}

// ---- pre-pass: wrel weights || cursor zero || x -> bf16 cast (R3-R6 verified) ----
__global__ __launch_bounds__(256) void k_pre(const float* __restrict__ x,
                                             const float* __restrict__ b1, const float* __restrict__ c1,
                                             const float* __restrict__ s1f,
                                             const float* __restrict__ b2, const float* __restrict__ c2,
                                             const float* __restrict__ s2f,
                                             unsigned short* __restrict__ w1T,
                                             unsigned short* __restrict__ w2T,
                                             unsigned short* __restrict__ xbf,
                                             int* __restrict__ cursor) {
    int bid = blockIdx.x;
    if (bid >= WREL_BLOCKS + ZERO_BLOCKS) {
        int i = (bid - WREL_BLOCKS - ZERO_BLOCKS) * 256 + threadIdx.x;
        if (i < 400000) {
            const float4* xs = (const float4*)x + (size_t)i * 2;
            float4 v0 = xs[0], v1 = xs[1];
            int4 w;
            w.x = (int)(((unsigned)f2bf(v0.y) << 16) | f2bf(v0.x));
            w.y = (int)(((unsigned)f2bf(v0.w) << 16) | f2bf(v0.z));
            w.z = (int)(((unsigned)f2bf(v1.y) << 16) | f2bf(v1.x));
            w.w = (int)(((unsigned)f2bf(v1.w) << 16) | f2bf(v1.z));
            *(int4*)(xbf + (size_t)i * 8) = w;
        }
        return;
    }
    if (bid >= WREL_BLOCKS) {
        int i = (bid - WREL_BLOCKS) * 256 + threadIdx.x;
        if (i < 12504) ((int4*)cursor)[i] = make_int4(0, 0, 0, 0);
        return;
    }
    int idx = bid * 256 + threadIdx.x;
    if (idx < 17 * 4096) {
        int r = idx >> 12, o = (idx >> 6) & 63, k = idx & 63;
        float acc = 0.f;
        if (r < 16) {
            #pragma unroll
            for (int b = 0; b < N_BASIS; b++) acc += c1[r * N_BASIS + b] * b1[b * 4096 + k * 64 + o];
        } else {
            acc = s1f[k * 64 + o];
        }
        w1T[idx] = f2bf(acc);
    } else {
        int idx2 = idx - 17 * 4096;
        if (idx2 < 17 * 1024) {
            int r = idx2 >> 10, o = (idx2 >> 6) & 15, k = idx2 & 63;
            float acc = 0.f;
            if (r < 16) {
                #pragma unroll
                for (int b = 0; b < N_BASIS; b++) acc += c2[r * N_BASIS + b] * b2[b * 1024 + k * 16 + o];
            } else {
                acc = s2f[k * 16 + o];
            }
            w2T[idx2] = f2bf(acc);
        }
    }
}

// ---- bucket scatter (R0-proven body) ----
__global__ __launch_bounds__(256) void k_scatter(const int* __restrict__ ei,
                                                 const int* __restrict__ et,
                                                 int* __restrict__ cursor,
                                                 int* __restrict__ sed) {
    int e = blockIdx.x * 256 + threadIdx.x;
    if (e < N_EDGES) {
        int src = ei[e];
        int dst = ei[N_EDGES + e];
        int t = et[e];
        int pos = atomicAdd(&cursor[dst], 1);
        if (pos < CAP) sed[dst * CAP + pos] = (t << 16) | src;
    }
}

// ---- LDS for k_agg1t: R4-proven AggLds (25,600 B) + htile (2,304 B) = 27,904 B ----
struct AggLds {
    int esrt[16][64];                                          // sorted packed (r<<16|src)
    int hist[16][16];
    int cur[16][16];
    int sta[16][16];
    __align__(16) unsigned short agg[2][4][16][72];            // dbuf x 4-rel x node x dim
    __align__(16) unsigned short htile[16][72];                // h tile (node-major, stride 72)
};

// ---- prologue: bucket -> regs, histogram, prefix, counting sort into esrt (R4-proven) ----
__device__ __forceinline__ void agg_prologue(AggLds& S, const int* __restrict__ cursor,
                                             const int* __restrict__ sed,
                                             int j, int sub, int n, int& deg) {
    deg = cursor[n];
    deg = deg < CAP ? deg : CAP;
    const int* bucket = sed + n * CAP;
    int be0 = (sub      < deg) ? bucket[sub]      : -1;
    int be1 = (sub + 16 < deg) ? bucket[sub + 16] : -1;
    int be2 = (sub + 32 < deg) ? bucket[sub + 32] : -1;
    int be3 = (sub + 48 < deg) ? bucket[sub + 48] : -1;
    S.hist[j][sub] = 0;
    __syncthreads();
    if (be0 >= 0) atomicAdd(&S.hist[j][be0 >> 16], 1);
    if (be1 >= 0) atomicAdd(&S.hist[j][be1 >> 16], 1);
    if (be2 >= 0) atomicAdd(&S.hist[j][be2 >> 16], 1);
    if (be3 >= 0) atomicAdd(&S.hist[j][be3 >> 16], 1);
    __syncthreads();
    {
        int st = 0;
        #pragma unroll
        for (int t = 0; t < 16; t++) { int hv = S.hist[j][t]; if (t < sub) st += hv; }
        S.sta[j][sub] = st;
        S.cur[j][sub] = st;
    }
    __syncthreads();
    if (be0 >= 0) { int p = atomicAdd(&S.cur[j][be0 >> 16], 1); S.esrt[j][p] = be0; }
    if (be1 >= 0) { int p = atomicAdd(&S.cur[j][be1 >> 16], 1); S.esrt[j][p] = be1; }
    if (be2 >= 0) { int p = atomicAdd(&S.cur[j][be2 >> 16], 1); S.esrt[j][p] = be2; }
    if (be3 >= 0) { int p = atomicAdd(&S.cur[j][be3 >> 16], 1); S.esrt[j][p] = be3; }
    __syncthreads();
}

// ---- one walk phase (R4-proven): edges [start,end) cover relations [rbase, rbase+4) ----
__device__ __forceinline__ void walk_phase(AggLds& S, const unsigned short* __restrict__ srcmat,
                                           int j, int sub, int start, int end, int rbase, int buf) {
    ushort4 z; z.x = 0; z.y = 0; z.z = 0; z.w = 0;
    #pragma unroll
    for (int rl = 0; rl < 4; rl++) *(ushort4*)&S.agg[buf][rl][j][sub * 4] = z;

    float a0 = 0.f, a1 = 0.f, a2 = 0.f, a3 = 0.f;
    int rprev = -1;
    auto flush = [&](int r) {
        float iv = 1.0f / (float)S.hist[j][r];
        ushort4 o;
        o.x = f2bf(a0 * iv); o.y = f2bf(a1 * iv); o.z = f2bf(a2 * iv); o.w = f2bf(a3 * iv);
        *(ushort4*)&S.agg[buf][r - rbase][j][sub * 4] = o;
    };
    auto proc = [&](int e, int2 p) {
        int r = e >> 16;
        if (r != rprev) {
            if (rprev >= 0) flush(rprev);
            a0 = a1 = a2 = a3 = 0.f;
            rprev = r;
        }
        a0 += bfLO(p.x); a1 += bfHI(p.x); a2 += bfLO(p.y); a3 += bfHI(p.y);
    };
    for (int ib = start; ib < end; ib += 4) {
        int rem = end - ib;
        int e0, e1 = 0, e2 = 0, e3 = 0;
        int2 p0, p1 = make_int2(0, 0), p2 = make_int2(0, 0), p3 = make_int2(0, 0);
        e0 = S.esrt[j][ib];
        p0 = *(const int2*)(srcmat + (e0 & 0xFFFF) * 64 + sub * 4);
        if (rem > 1) { e1 = S.esrt[j][ib + 1]; p1 = *(const int2*)(srcmat + (e1 & 0xFFFF) * 64 + sub * 4); }
        if (rem > 2) { e2 = S.esrt[j][ib + 2]; p2 = *(const int2*)(srcmat + (e2 & 0xFFFF) * 64 + sub * 4); }
        if (rem > 3) { e3 = S.esrt[j][ib + 3]; p3 = *(const int2*)(srcmat + (e3 & 0xFFFF) * 64 + sub * 4); }
        proc(e0, p0);
        if (rem > 1) proc(e1, p1);
        if (rem > 2) proc(e2, p2);
        if (rem > 3) proc(e3, p3);
    }
    if (rprev >= 0) flush(rprev);
}

// ---- MFMA consume of one 4-relation buffer (R4-proven) ----
__device__ __forceinline__ void mfma4(AggLds& S, const unsigned short* __restrict__ wpA,
                                      int rbase, int buf, int m, int q, f4v& D) {
    #pragma unroll
    for (int rl = 0; rl < 4; rl++) {
        int r = rbase + rl;
        s8v A0 = *(const s8v*)(wpA + r * 4096);
        s8v A1 = *(const s8v*)(wpA + r * 4096 + 32);
        s8v B0 = *(const s8v*)&S.agg[buf][rl][m][q * 8];
        s8v B1 = *(const s8v*)&S.agg[buf][rl][m][32 + q * 8];
        D = __builtin_amdgcn_mfma_f32_16x16x32_bf16(A0, B0, D, 0, 0, 0);
        D = __builtin_amdgcn_mfma_f32_16x16x32_bf16(A1, B1, D, 0, 0, 0);
    }
}

// ---- fused: layer-1 agg (R4-proven walk) + W1-MFMA + relu -> htile LDS,
//      then layer-2 transform (R0 k_aggt phase-2, verified): t2 slots + self -> out ----
__global__ __launch_bounds__(256) void k_agg1t(const int* __restrict__ cursor,
                                               const int* __restrict__ sed,
                                               const unsigned short* __restrict__ xbf,
                                               const unsigned short* __restrict__ w1T,
                                               const unsigned short* __restrict__ w2T,
                                               unsigned short* __restrict__ t2,
                                               float* __restrict__ out) {
    __shared__ AggLds S;
    int tid = threadIdx.x;
    int j = tid >> 4, sub = tid & 15;
    int nb = blockIdx.x * 16;
    int n = nb + j;
    int deg;
    agg_prologue(S, cursor, sed, j, sub, n, deg);

    int b1p = S.sta[j][4], b2p = S.sta[j][8], b3p = S.sta[j][12];
    int wv = tid >> 6, lane = tid & 63;
    int m = lane & 15, q = lane >> 4;
    int nn = nb + m;
    const unsigned short* wpA = w1T + (wv * 16 + m) * 64 + q * 8;   // A[o=wv*16+m][k]
    f4v D = (f4v){0.f, 0.f, 0.f, 0.f};

    walk_phase(S, xbf, j, sub, 0,   b1p, 0,  0);                 // region 0: write buf0
    __syncthreads();
    walk_phase(S, xbf, j, sub, b1p, b2p, 4,  1);                 // region 1: write buf1
    mfma4(S, wpA, 0, 0, m, q, D);                                //           read  buf0
    __syncthreads();
    walk_phase(S, xbf, j, sub, b2p, b3p, 8,  0);                 // region 2: write buf0
    mfma4(S, wpA, 4, 1, m, q, D);                                //           read  buf1
    __syncthreads();
    walk_phase(S, xbf, j, sub, b3p, deg, 12, 1);                 // region 3: write buf1
    mfma4(S, wpA, 8, 0, m, q, D);                                //           read  buf0
    __syncthreads();
    mfma4(S, wpA, 12, 1, m, q, D);                               // region 4: read buf1

    {   // self term: relation slot 16, B straight from xbf
        s8v A0 = *(const s8v*)(wpA + 16 * 4096);
        s8v A1 = *(const s8v*)(wpA + 16 * 4096 + 32);
        s8v B0 = *(const s8v*)(xbf + (size_t)nn * 64 + q * 8);
        s8v B1 = *(const s8v*)(xbf + (size_t)nn * 64 + 32 + q * 8);
        D = __builtin_amdgcn_mfma_f32_16x16x32_bf16(A0, B0, D, 0, 0, 0);
        D = __builtin_amdgcn_mfma_f32_16x16x32_bf16(A1, B1, D, 0, 0, 0);
    }
    ushort4 o;
    o.x = f2bf(D[0] > 0.f ? D[0] : 0.f);
    o.y = f2bf(D[1] > 0.f ? D[1] : 0.f);
    o.z = f2bf(D[2] > 0.f ? D[2] : 0.f);
    o.w = f2bf(D[3] > 0.f ? D[3] : 0.f);
    *(ushort4*)&S.htile[m][wv * 16 + q * 4] = o;   // D col=m(node), row=q*4+i(dim); R6-verified
    __syncthreads();

    // ---- stage 2 (R0 k_aggt phase-2, verified): 4 t2 slots per wave + self on wave0 ----
    {
        const unsigned short* wp2 = w2T + m * 64 + q * 8;   // A[o=m][k]
        s8v b0 = *(const s8v*)&S.htile[m][q * 8];
        s8v b1 = *(const s8v*)&S.htile[m][32 + q * 8];
        #pragma unroll
        for (int j5 = 0; j5 < 4; j5++) {
            int w = wv * 4 + j5;
            s8v A0 = *(const s8v*)(wp2 + (w << 10));
            s8v A1 = *(const s8v*)(wp2 + (w << 10) + 32);
            f4v acc = (f4v){0.f, 0.f, 0.f, 0.f};
            acc = __builtin_amdgcn_mfma_f32_16x16x32_bf16(A0, b0, acc, 0, 0, 0);
            acc = __builtin_amdgcn_mfma_f32_16x16x32_bf16(A1, b1, acc, 0, 0, 0);
            ushort4 o4;
            o4.x = f2bf(acc[0]); o4.y = f2bf(acc[1]); o4.z = f2bf(acc[2]); o4.w = f2bf(acc[3]);
            *(ushort4*)(t2 + ((size_t)w * N_NODES + nn) * 16 + q * 4) = o4;
        }
        if (wv == 0) {   // self slot -> out (fp32)
            s8v A0 = *(const s8v*)(wp2 + (16 << 10));
            s8v A1 = *(const s8v*)(wp2 + (16 << 10) + 32);
            f4v acc = (f4v){0.f, 0.f, 0.f, 0.f};
            acc = __builtin_amdgcn_mfma_f32_16x16x32_bf16(A0, b0, acc, 0, 0, 0);
            acc = __builtin_amdgcn_mfma_f32_16x16x32_bf16(A1, b1, acc, 0, 0, 0);
            *(float4*)(out + (size_t)nn * 16 + q * 4) = make_float4(acc[0], acc[1], acc[2], acc[3]);
        }
    }
}

// ---- layer-2 aggregation (R0-proven + barriers, R6-verified):
//      16 lanes/node, 8 slots x unroll-2, LDS hist; gathers 32B t2 rows, += out ----
__global__ __launch_bounds__(256) void k_agg2(const int* __restrict__ cursor,
                                              const int* __restrict__ sed,
                                              const unsigned short* __restrict__ t2,
                                              float* __restrict__ out) {
    __shared__ int hist[16][16];
    int tid = threadIdx.x;
    int j = tid >> 4;          // node in block 0..15
    int sub = tid & 15;
    int n = blockIdx.x * 16 + j;   // 3125*16 = 50000 exact
    int deg = cursor[n];
    deg = deg < CAP ? deg : CAP;
    const int* bucket = sed + n * CAP;

    hist[j][sub] = 0;
    __syncthreads();
    for (int i = sub; i < deg; i += 16)
        atomicAdd(&hist[j][bucket[i] >> 16], 1);
    __syncthreads();

    int slot = sub >> 1;       // edge slot 0..7
    int d2 = sub & 1;          // dim half: 8 bf16
    float a[8];
    #pragma unroll
    for (int k = 0; k < 8; k++) a[k] = 0.f;
    for (int i = slot; i < deg; i += 16) {
        int e0 = bucket[i];
        bool has1 = (i + 8) < deg;
        int e1 = has1 ? bucket[i + 8] : e0;
        int t0 = e0 >> 16, s0 = e0 & 0xFFFF;
        int t1i = e1 >> 16, s1 = e1 & 0xFFFF;
        float inv0 = 1.0f / (float)hist[j][t0];
        float inv1 = has1 ? (1.0f / (float)hist[j][t1i]) : 0.f;
        int4 p0 = *(const int4*)(t2 + ((size_t)(t0 * N_NODES + s0)) * 16 + d2 * 8);
        int4 p1 = *(const int4*)(t2 + ((size_t)(t1i * N_NODES + s1)) * 16 + d2 * 8);
        acc8(a, inv0, p0);
        acc8(a, inv1, p1);
    }
    #pragma unroll
    for (int k = 0; k < 8; k++) {
        a[k] += __shfl_xor(a[k], 2, 64);
        a[k] += __shfl_xor(a[k], 4, 64);
        a[k] += __shfl_xor(a[k], 8, 64);
    }
    if (slot == 0) {
        float* p = out + (size_t)n * 16 + d2 * 8;
        float4 c0 = *(const float4*)p;
        float4 c1 = *(const float4*)(p + 4);
        c0.x += a[0]; c0.y += a[1]; c0.z += a[2]; c0.w += a[3];
        c1.x += a[4]; c1.y += a[5]; c1.z += a[6]; c1.w += a[7];
        *(float4*)p = c0;
        *(float4*)(p + 4) = c1;
    }
}

extern "C" void kernel_launch(void* const* d_in, const int* in_sizes, int n_in,
                              void* d_out, int out_size, void* d_ws, size_t ws_size,
                              hipStream_t stream) {
    const float* x      = (const float*)d_in[0];
    const float* bases1 = (const float*)d_in[1];
    const float* coeffs1= (const float*)d_in[2];
    const float* self1  = (const float*)d_in[3];
    const float* bases2 = (const float*)d_in[4];
    const float* coeffs2= (const float*)d_in[5];
    const float* self2  = (const float*)d_in[6];
    const int*   ei     = (const int*)d_in[7];
    const int*   et     = (const int*)d_in[8];
    float* out = (float*)d_out;

    char* ws = (char*)d_ws;
    int*            cursor = (int*)(ws + 0);                    //    200,064 (50,016 ints, zeroed)
    unsigned short* w1T    = (unsigned short*)(ws + 200064);    //    139,264
    unsigned short* w2T    = (unsigned short*)(ws + 339328);    //     34,816
    int*            sed    = (int*)(ws + 374144);               // 12,800,000 (50000 x 64 x 4B)
    unsigned short* xbf    = (unsigned short*)(ws + 13174144);  //  6,400,000 (50,000 rows x 128B)
    unsigned short* t2     = (unsigned short*)(ws + 19574144);  // 25,600,000 -> 45,174,144

    k_pre<<<WREL_BLOCKS + ZERO_BLOCKS + XBF_BLOCKS, 256, 0, stream>>>(
        x, bases1, coeffs1, self1, bases2, coeffs2, self2, w1T, w2T, xbf, cursor);
    k_scatter<<<SC_BLOCKS, 256, 0, stream>>>(ei, et, cursor, sed);
    k_agg1t<<<AGG_BLOCKS, 256, 0, stream>>>(cursor, sed, xbf, w1T, w2T, t2, out);
    k_agg2<<<AGG_BLOCKS, 256, 0, stream>>>(cursor, sed, t2, out);
}

// Round 8
// 233.338 us; speedup vs baseline: 2.2774x; 1.0104x over previous
//
#include <hip/hip_runtime.h>

#define N_NODES 50000
#define N_REL 16
#define N_BASIS 8
#define N_EDGES 800000
#define CAP 64              // bucket capacity; deg ~ Poisson(16), P(>64) ~ 1e-19

#define WREL_BLOCKS 340     // (17*4096 + 17*1024)/256
#define ZERO_BLOCKS 49      // ceil(12504 int4 / 256)
#define XBF_BLOCKS 1563     // ceil(400000 / 256)  (50000*64 / 8 per thread)
#define SC_BLOCKS 3125      // 800000 / 256
#define AGG_BLOCKS 3125     // 50000 / 16 exact

typedef short s8v __attribute__((ext_vector_type(8)));    // 8 bf16 MFMA A/B frag
typedef float f4v __attribute__((ext_vector_type(4)));    // 4 fp32 MFMA C/D frag

__device__ inline unsigned short f2bf(float f) {
    union { float f; unsigned u; } v; v.f = f;
    unsigned r = (v.u + 0x7FFFu + ((v.u >> 16) & 1u)) >> 16;   // RNE
    return (unsigned short)r;
}
__device__ __forceinline__ float bfLO(int w) { return __int_as_float((int)((unsigned)w << 16)); }
__device__ __forceinline__ float bfHI(int w) { return __int_as_float(w & (int)0xFFFF0000u); }

// a[0..7] += inv * (8 bf16 packed in int4)   (R0-proven helper for k_agg2)
__device__ __forceinline__ void acc8(float* a, float inv, int4 p) {
    a[0] += inv * __int_as_float((int)((unsigned)p.x << 16));
    a[1] += inv * __int_as_float(p.x & (int)0xFFFF0000u);
    a[2] += inv * __int_as_float((int)((unsigned)p.y << 16));
    a[3] += inv * __int_as_float(p.y & (int)0xFFFF0000u);
    a[4] += inv * __int_as_float((int)((unsigned)p.z << 16));
    a[5] += inv * __int_as_float(p.z & (int)0xFFFF0000u);
    a[6] += inv * __int_as_float((int)((unsigned)p.w << 16));
    a[7] += inv * __int_as_float(p.w & (int)0xFFFF0000u);
}

// ---- pre-pass: wrel weights || cursor zero || x -> bf16 cast (R3-R7 verified) ----
__global__ __launch_bounds__(256) void k_pre(const float* __restrict__ x,
                                             const float* __restrict__ b1, const float* __restrict__ c1,
                                             const float* __restrict__ s1f,
                                             const float* __restrict__ b2, const float* __restrict__ c2,
                                             const float* __restrict__ s2f,
                                             unsigned short* __restrict__ w1T,
                                             unsigned short* __restrict__ w2T,
                                             unsigned short* __restrict__ xbf,
                                             int* __restrict__ cursor) {
    int bid = blockIdx.x;
    if (bid >= WREL_BLOCKS + ZERO_BLOCKS) {
        int i = (bid - WREL_BLOCKS - ZERO_BLOCKS) * 256 + threadIdx.x;
        if (i < 400000) {
            const float4* xs = (const float4*)x + (size_t)i * 2;
            float4 v0 = xs[0], v1 = xs[1];
            int4 w;
            w.x = (int)(((unsigned)f2bf(v0.y) << 16) | f2bf(v0.x));
            w.y = (int)(((unsigned)f2bf(v0.w) << 16) | f2bf(v0.z));
            w.z = (int)(((unsigned)f2bf(v1.y) << 16) | f2bf(v1.x));
            w.w = (int)(((unsigned)f2bf(v1.w) << 16) | f2bf(v1.z));
            *(int4*)(xbf + (size_t)i * 8) = w;
        }
        return;
    }
    if (bid >= WREL_BLOCKS) {
        int i = (bid - WREL_BLOCKS) * 256 + threadIdx.x;
        if (i < 12504) ((int4*)cursor)[i] = make_int4(0, 0, 0, 0);
        return;
    }
    int idx = bid * 256 + threadIdx.x;
    if (idx < 17 * 4096) {
        int r = idx >> 12, o = (idx >> 6) & 63, k = idx & 63;
        float acc = 0.f;
        if (r < 16) {
            #pragma unroll
            for (int b = 0; b < N_BASIS; b++) acc += c1[r * N_BASIS + b] * b1[b * 4096 + k * 64 + o];
        } else {
            acc = s1f[k * 64 + o];
        }
        w1T[idx] = f2bf(acc);
    } else {
        int idx2 = idx - 17 * 4096;
        if (idx2 < 17 * 1024) {
            int r = idx2 >> 10, o = (idx2 >> 6) & 15, k = idx2 & 63;
            float acc = 0.f;
            if (r < 16) {
                #pragma unroll
                for (int b = 0; b < N_BASIS; b++) acc += c2[r * N_BASIS + b] * b2[b * 1024 + k * 16 + o];
            } else {
                acc = s2f[k * 16 + o];
            }
            w2T[idx2] = f2bf(acc);
        }
    }
}

// ---- bucket scatter (R0-proven body) ----
__global__ __launch_bounds__(256) void k_scatter(const int* __restrict__ ei,
                                                 const int* __restrict__ et,
                                                 int* __restrict__ cursor,
                                                 int* __restrict__ sed) {
    int e = blockIdx.x * 256 + threadIdx.x;
    if (e < N_EDGES) {
        int src = ei[e];
        int dst = ei[N_EDGES + e];
        int t = et[e];
        int pos = atomicAdd(&cursor[dst], 1);
        if (pos < CAP) sed[dst * CAP + pos] = (t << 16) | src;
    }
}

// ---- LDS for k_agg1t: htile OVERLAYS agg[0] (dead by the time htile is written).
//      Total 25,600 B -> 6 blocks/CU (R4-proven occupancy). ----
struct AggLds {
    int esrt[16][64];                                          // sorted packed (r<<16|src)
    int hist[16][16];
    int cur[16][16];
    int sta[16][16];
    union __align__(16) {
        unsigned short agg[2][4][16][72];                      // dbuf x 4-rel x node x dim
        unsigned short htile[16][72];                          // overlays agg[0] (2304 B of 9216 B)
    } u;
};

// ---- prologue: bucket -> regs, histogram, prefix, counting sort into esrt (R4/R7-proven)
//      + NEW: export inv table (1/cnt) for k_agg2 ----
__device__ __forceinline__ void agg_prologue(AggLds& S, const int* __restrict__ cursor,
                                             const int* __restrict__ sed,
                                             float* __restrict__ invtab,
                                             int j, int sub, int n, int& deg) {
    deg = cursor[n];
    deg = deg < CAP ? deg : CAP;
    const int* bucket = sed + n * CAP;
    int be0 = (sub      < deg) ? bucket[sub]      : -1;
    int be1 = (sub + 16 < deg) ? bucket[sub + 16] : -1;
    int be2 = (sub + 32 < deg) ? bucket[sub + 32] : -1;
    int be3 = (sub + 48 < deg) ? bucket[sub + 48] : -1;
    S.hist[j][sub] = 0;
    __syncthreads();
    if (be0 >= 0) atomicAdd(&S.hist[j][be0 >> 16], 1);
    if (be1 >= 0) atomicAdd(&S.hist[j][be1 >> 16], 1);
    if (be2 >= 0) atomicAdd(&S.hist[j][be2 >> 16], 1);
    if (be3 >= 0) atomicAdd(&S.hist[j][be3 >> 16], 1);
    __syncthreads();
    {
        int st = 0, own = 0;
        #pragma unroll
        for (int t = 0; t < 16; t++) {
            int hv = S.hist[j][t];
            if (t < sub) st += hv;
            if (t == sub) own = hv;
        }
        S.sta[j][sub] = st;
        S.cur[j][sub] = st;
        invtab[n * 16 + sub] = 1.0f / (float)(own > 0 ? own : 1);   // coalesced 1KB/block
    }
    __syncthreads();
    if (be0 >= 0) { int p = atomicAdd(&S.cur[j][be0 >> 16], 1); S.esrt[j][p] = be0; }
    if (be1 >= 0) { int p = atomicAdd(&S.cur[j][be1 >> 16], 1); S.esrt[j][p] = be1; }
    if (be2 >= 0) { int p = atomicAdd(&S.cur[j][be2 >> 16], 1); S.esrt[j][p] = be2; }
    if (be3 >= 0) { int p = atomicAdd(&S.cur[j][be3 >> 16], 1); S.esrt[j][p] = be3; }
    __syncthreads();
}

// ---- one walk phase (R4/R7-proven): edges [start,end) cover relations [rbase, rbase+4) ----
__device__ __forceinline__ void walk_phase(AggLds& S, const unsigned short* __restrict__ srcmat,
                                           int j, int sub, int start, int end, int rbase, int buf) {
    ushort4 z; z.x = 0; z.y = 0; z.z = 0; z.w = 0;
    #pragma unroll
    for (int rl = 0; rl < 4; rl++) *(ushort4*)&S.u.agg[buf][rl][j][sub * 4] = z;

    float a0 = 0.f, a1 = 0.f, a2 = 0.f, a3 = 0.f;
    int rprev = -1;
    auto flush = [&](int r) {
        float iv = 1.0f / (float)S.hist[j][r];
        ushort4 o;
        o.x = f2bf(a0 * iv); o.y = f2bf(a1 * iv); o.z = f2bf(a2 * iv); o.w = f2bf(a3 * iv);
        *(ushort4*)&S.u.agg[buf][r - rbase][j][sub * 4] = o;
    };
    auto proc = [&](int e, int2 p) {
        int r = e >> 16;
        if (r != rprev) {
            if (rprev >= 0) flush(rprev);
            a0 = a1 = a2 = a3 = 0.f;
            rprev = r;
        }
        a0 += bfLO(p.x); a1 += bfHI(p.x); a2 += bfLO(p.y); a3 += bfHI(p.y);
    };
    for (int ib = start; ib < end; ib += 4) {
        int rem = end - ib;
        int e0, e1 = 0, e2 = 0, e3 = 0;
        int2 p0, p1 = make_int2(0, 0), p2 = make_int2(0, 0), p3 = make_int2(0, 0);
        e0 = S.esrt[j][ib];
        p0 = *(const int2*)(srcmat + (e0 & 0xFFFF) * 64 + sub * 4);
        if (rem > 1) { e1 = S.esrt[j][ib + 1]; p1 = *(const int2*)(srcmat + (e1 & 0xFFFF) * 64 + sub * 4); }
        if (rem > 2) { e2 = S.esrt[j][ib + 2]; p2 = *(const int2*)(srcmat + (e2 & 0xFFFF) * 64 + sub * 4); }
        if (rem > 3) { e3 = S.esrt[j][ib + 3]; p3 = *(const int2*)(srcmat + (e3 & 0xFFFF) * 64 + sub * 4); }
        proc(e0, p0);
        if (rem > 1) proc(e1, p1);
        if (rem > 2) proc(e2, p2);
        if (rem > 3) proc(e3, p3);
    }
    if (rprev >= 0) flush(rprev);
}

// ---- MFMA consume of one 4-relation buffer (R4/R7-proven) ----
__device__ __forceinline__ void mfma4(AggLds& S, const unsigned short* __restrict__ wpA,
                                      int rbase, int buf, int m, int q, f4v& D) {
    #pragma unroll
    for (int rl = 0; rl < 4; rl++) {
        int r = rbase + rl;
        s8v A0 = *(const s8v*)(wpA + r * 4096);
        s8v A1 = *(const s8v*)(wpA + r * 4096 + 32);
        s8v B0 = *(const s8v*)&S.u.agg[buf][rl][m][q * 8];
        s8v B1 = *(const s8v*)&S.u.agg[buf][rl][m][32 + q * 8];
        D = __builtin_amdgcn_mfma_f32_16x16x32_bf16(A0, B0, D, 0, 0, 0);
        D = __builtin_amdgcn_mfma_f32_16x16x32_bf16(A1, B1, D, 0, 0, 0);
    }
}

// ---- fused: layer-1 agg (R4-proven walk) + W1-MFMA + relu -> htile LDS,
//      then layer-2 transform (R0 k_aggt phase-2, R7-verified): t2 slots + self -> out ----
__global__ __launch_bounds__(256) void k_agg1t(const int* __restrict__ cursor,
                                               const int* __restrict__ sed,
                                               const unsigned short* __restrict__ xbf,
                                               const unsigned short* __restrict__ w1T,
                                               const unsigned short* __restrict__ w2T,
                                               unsigned short* __restrict__ t2,
                                               float* __restrict__ invtab,
                                               float* __restrict__ out) {
    __shared__ AggLds S;
    int tid = threadIdx.x;
    int j = tid >> 4, sub = tid & 15;
    int nb = blockIdx.x * 16;
    int n = nb + j;
    int deg;
    agg_prologue(S, cursor, sed, invtab, j, sub, n, deg);

    int b1p = S.sta[j][4], b2p = S.sta[j][8], b3p = S.sta[j][12];
    int wv = tid >> 6, lane = tid & 63;
    int m = lane & 15, q = lane >> 4;
    int nn = nb + m;
    const unsigned short* wpA = w1T + (wv * 16 + m) * 64 + q * 8;   // A[o=wv*16+m][k]
    f4v D = (f4v){0.f, 0.f, 0.f, 0.f};

    walk_phase(S, xbf, j, sub, 0,   b1p, 0,  0);                 // region 0: write buf0
    __syncthreads();
    walk_phase(S, xbf, j, sub, b1p, b2p, 4,  1);                 // region 1: write buf1
    mfma4(S, wpA, 0, 0, m, q, D);                                //           read  buf0
    __syncthreads();
    walk_phase(S, xbf, j, sub, b2p, b3p, 8,  0);                 // region 2: write buf0
    mfma4(S, wpA, 4, 1, m, q, D);                                //           read  buf1
    __syncthreads();
    walk_phase(S, xbf, j, sub, b3p, deg, 12, 1);                 // region 3: write buf1
    mfma4(S, wpA, 8, 0, m, q, D);                                //           read  buf0 (LAST agg[0] read)
    __syncthreads();
    mfma4(S, wpA, 12, 1, m, q, D);                               // region 4: read buf1

    {   // self term: relation slot 16, B straight from xbf
        s8v A0 = *(const s8v*)(wpA + 16 * 4096);
        s8v A1 = *(const s8v*)(wpA + 16 * 4096 + 32);
        s8v B0 = *(const s8v*)(xbf + (size_t)nn * 64 + q * 8);
        s8v B1 = *(const s8v*)(xbf + (size_t)nn * 64 + 32 + q * 8);
        D = __builtin_amdgcn_mfma_f32_16x16x32_bf16(A0, B0, D, 0, 0, 0);
        D = __builtin_amdgcn_mfma_f32_16x16x32_bf16(A1, B1, D, 0, 0, 0);
    }
    ushort4 o;
    o.x = f2bf(D[0] > 0.f ? D[0] : 0.f);
    o.y = f2bf(D[1] > 0.f ? D[1] : 0.f);
    o.z = f2bf(D[2] > 0.f ? D[2] : 0.f);
    o.w = f2bf(D[3] > 0.f ? D[3] : 0.f);
    // htile overlays agg[0]; its last read was before the previous barrier -> safe
    *(ushort4*)&S.u.htile[m][wv * 16 + q * 4] = o;   // D col=m(node), row=q*4+i(dim); R6/R7-verified
    __syncthreads();

    // ---- stage 2 (R0 k_aggt phase-2, R7-verified): 4 t2 slots per wave + self on wave0 ----
    {
        const unsigned short* wp2 = w2T + m * 64 + q * 8;   // A[o=m][k]
        s8v b0 = *(const s8v*)&S.u.htile[m][q * 8];
        s8v b1 = *(const s8v*)&S.u.htile[m][32 + q * 8];
        #pragma unroll
        for (int j5 = 0; j5 < 4; j5++) {
            int w = wv * 4 + j5;
            s8v A0 = *(const s8v*)(wp2 + (w << 10));
            s8v A1 = *(const s8v*)(wp2 + (w << 10) + 32);
            f4v acc = (f4v){0.f, 0.f, 0.f, 0.f};
            acc = __builtin_amdgcn_mfma_f32_16x16x32_bf16(A0, b0, acc, 0, 0, 0);
            acc = __builtin_amdgcn_mfma_f32_16x16x32_bf16(A1, b1, acc, 0, 0, 0);
            ushort4 o4;
            o4.x = f2bf(acc[0]); o4.y = f2bf(acc[1]); o4.z = f2bf(acc[2]); o4.w = f2bf(acc[3]);
            *(ushort4*)(t2 + ((size_t)w * N_NODES + nn) * 16 + q * 4) = o4;
        }
        if (wv == 0) {   // self slot -> out (fp32)
            s8v A0 = *(const s8v*)(wp2 + (16 << 10));
            s8v A1 = *(const s8v*)(wp2 + (16 << 10) + 32);
            f4v acc = (f4v){0.f, 0.f, 0.f, 0.f};
            acc = __builtin_amdgcn_mfma_f32_16x16x32_bf16(A0, b0, acc, 0, 0, 0);
            acc = __builtin_amdgcn_mfma_f32_16x16x32_bf16(A1, b1, acc, 0, 0, 0);
            *(float4*)(out + (size_t)nn * 16 + q * 4) = make_float4(acc[0], acc[1], acc[2], acc[3]);
        }
    }
}

// ---- layer-2 aggregation (R0/R7-proven gather; prologue replaced by invtab load):
//      16 lanes/node, 8 slots x unroll-2; gathers 32B t2 rows, += out ----
__global__ __launch_bounds__(256) void k_agg2(const int* __restrict__ cursor,
                                              const int* __restrict__ sed,
                                              const unsigned short* __restrict__ t2,
                                              const float* __restrict__ invtab,
                                              float* __restrict__ out) {
    __shared__ float hinv[16][16];
    int tid = threadIdx.x;
    int j = tid >> 4;          // node in block 0..15
    int sub = tid & 15;
    int n = blockIdx.x * 16 + j;   // 3125*16 = 50000 exact
    int deg = cursor[n];
    deg = deg < CAP ? deg : CAP;
    const int* bucket = sed + n * CAP;

    hinv[j][sub] = invtab[n * 16 + sub];    // coalesced; counts from k_agg1t (same buckets)
    __syncthreads();

    int slot = sub >> 1;       // edge slot 0..7
    int d2 = sub & 1;          // dim half: 8 bf16
    float a[8];
    #pragma unroll
    for (int k = 0; k < 8; k++) a[k] = 0.f;
    for (int i = slot; i < deg; i += 16) {
        int e0 = bucket[i];
        bool has1 = (i + 8) < deg;
        int e1 = has1 ? bucket[i + 8] : e0;
        int t0 = e0 >> 16, s0 = e0 & 0xFFFF;
        int t1i = e1 >> 16, s1 = e1 & 0xFFFF;
        float inv0 = hinv[j][t0];
        float inv1 = has1 ? hinv[j][t1i] : 0.f;
        int4 p0 = *(const int4*)(t2 + ((size_t)(t0 * N_NODES + s0)) * 16 + d2 * 8);
        int4 p1 = *(const int4*)(t2 + ((size_t)(t1i * N_NODES + s1)) * 16 + d2 * 8);
        acc8(a, inv0, p0);
        acc8(a, inv1, p1);
    }
    #pragma unroll
    for (int k = 0; k < 8; k++) {
        a[k] += __shfl_xor(a[k], 2, 64);
        a[k] += __shfl_xor(a[k], 4, 64);
        a[k] += __shfl_xor(a[k], 8, 64);
    }
    if (slot == 0) {
        float* p = out + (size_t)n * 16 + d2 * 8;
        float4 c0 = *(const float4*)p;
        float4 c1 = *(const float4*)(p + 4);
        c0.x += a[0]; c0.y += a[1]; c0.z += a[2]; c0.w += a[3];
        c1.x += a[4]; c1.y += a[5]; c1.z += a[6]; c1.w += a[7];
        *(float4*)p = c0;
        *(float4*)(p + 4) = c1;
    }
}

extern "C" void kernel_launch(void* const* d_in, const int* in_sizes, int n_in,
                              void* d_out, int out_size, void* d_ws, size_t ws_size,
                              hipStream_t stream) {
    const float* x      = (const float*)d_in[0];
    const float* bases1 = (const float*)d_in[1];
    const float* coeffs1= (const float*)d_in[2];
    const float* self1  = (const float*)d_in[3];
    const float* bases2 = (const float*)d_in[4];
    const float* coeffs2= (const float*)d_in[5];
    const float* self2  = (const float*)d_in[6];
    const int*   ei     = (const int*)d_in[7];
    const int*   et     = (const int*)d_in[8];
    float* out = (float*)d_out;

    char* ws = (char*)d_ws;
    int*            cursor = (int*)(ws + 0);                    //    200,064 (50,016 ints, zeroed)
    unsigned short* w1T    = (unsigned short*)(ws + 200064);    //    139,264
    unsigned short* w2T    = (unsigned short*)(ws + 339328);    //     34,816
    int*            sed    = (int*)(ws + 374144);               // 12,800,000 (50000 x 64 x 4B)
    unsigned short* xbf    = (unsigned short*)(ws + 13174144);  //  6,400,000 (50,000 rows x 128B)
    unsigned short* t2     = (unsigned short*)(ws + 19574144);  // 25,600,000 -> 45,174,144
    float*          invtab = (float*)(ws + 45174144);           //  3,200,000 -> 48,374,144

    k_pre<<<WREL_BLOCKS + ZERO_BLOCKS + XBF_BLOCKS, 256, 0, stream>>>(
        x, bases1, coeffs1, self1, bases2, coeffs2, self2, w1T, w2T, xbf, cursor);
    k_scatter<<<SC_BLOCKS, 256, 0, stream>>>(ei, et, cursor, sed);
    k_agg1t<<<AGG_BLOCKS, 256, 0, stream>>>(cursor, sed, xbf, w1T, w2T, t2, invtab, out);
    k_agg2<<<AGG_BLOCKS, 256, 0, stream>>>(cursor, sed, t2, invtab, out);
}